// Round 11
// baseline (275.997 us; speedup 1.0000x reference)
//
#include <hip/hip_runtime.h>
#include <hip/hip_bf16.h>
#include <stdint.h>

#define T      3072
#define CH     64
#define HEADS  32
#define BM     128
#define BN     64
#define NIT    (T / BN)

typedef unsigned short u16;
typedef short short8 __attribute__((ext_vector_type(8)));   // 8 bf16 as i16
typedef float floatx4 __attribute__((ext_vector_type(4)));

__device__ __forceinline__ unsigned pk2(float a, float b) {  // 2 fp32 -> packed bf16x2 (RNE)
  union { __hip_bfloat162 h; unsigned u; } cv;
  cv.h = __float22bfloat162_rn(float2{a, b});
  return cv.u;
}

__device__ __forceinline__ void gl_lds16(const void* g, void* l) {
  __builtin_amdgcn_global_load_lds(
      (const __attribute__((address_space(1))) uint32_t*)g,
      (__attribute__((address_space(3))) uint32_t*)l, 16, 0, 0);
}

// Cross-quad exchanges (VALU, gfx950): swap rows crosswise between two VGPRs.
__device__ __forceinline__ void pl32swap(unsigned& x, unsigned& y) {
#if __has_builtin(__builtin_amdgcn_permlane32_swap)
  auto r = __builtin_amdgcn_permlane32_swap(x, y, false, false);
  x = r[0]; y = r[1];
#else
  asm("v_permlane32_swap_b32 %0, %1" : "+v"(x), "+v"(y));
#endif
}
__device__ __forceinline__ void pl16swap(unsigned& x, unsigned& y) {
#if __has_builtin(__builtin_amdgcn_permlane16_swap)
  auto r = __builtin_amdgcn_permlane16_swap(x, y, false, false);
  x = r[0]; y = r[1];
#else
  asm("v_permlane16_swap_b32 %0, %1" : "+v"(x), "+v"(y));
#endif
}

// ---------- prepass: Q/K transpose (ch,t)->(t,ch) + V flat cast, all bf16 ----------
// grid (48 t-tiles, 32 heads, 3 roles), 256 threads   [round-3 verified version]
__global__ __launch_bounds__(256) void qktrans(
    const float* __restrict__ qkv, u16* __restrict__ Qt, u16* __restrict__ Kt,
    u16* __restrict__ Vo) {
  __shared__ __align__(16) u16 tl[64][72];            // [t][c], pad to 144B stride
  const int ttile = blockIdx.x, hh = blockIdx.y, role = blockIdx.z;
  const int b = hh >> 3, h = hh & 7;
  const int t0 = ttile * 64;
  const int tid = threadIdx.x;

  if (role == 2) {                                     // V: no transpose, flat cast
    const float* vsrc = qkv + (size_t)(b * 1536 + 1024 + h * CH) * T;
    u16* vdst = Vo + (size_t)(b * 512 + h * CH) * T;
#pragma unroll
    for (int p = 0; p < 2; ++p) {
      const int r = p * 32 + (tid >> 3);
      const int off = (tid & 7) * 8;
      const float4* s4 = (const float4*)(vsrc + (size_t)r * T + t0 + off);
      float4 a = s4[0], c = s4[1];
      uint4 o;
      o.x = pk2(a.x, a.y); o.y = pk2(a.z, a.w);
      o.z = pk2(c.x, c.y); o.w = pk2(c.z, c.w);
      *(uint4*)(vdst + (size_t)r * T + t0 + off) = o;
    }
    return;
  }

  const float* src = qkv + (size_t)(b * 1536 + role * 512 + h * CH) * T;
  const float scale = (role == 0) ? 0.18033688011112042f : 1.0f;  // (1/8)*log2e on Q

#pragma unroll
  for (int p = 0; p < 2; ++p) {                        // 32 c-rows per pass
    const int c0 = p * 32 + ((tid >> 4) << 1);         // even
    const int ts = (tid & 15) * 4;                     // 256B contiguous per c-row
    float4 a = *(const float4*)(src + (size_t)c0 * T + t0 + ts);
    float4 c = *(const float4*)(src + (size_t)(c0 + 1) * T + t0 + ts);
    *(unsigned*)&tl[ts + 0][c0] = pk2(a.x * scale, c.x * scale);
    *(unsigned*)&tl[ts + 1][c0] = pk2(a.y * scale, c.y * scale);
    *(unsigned*)&tl[ts + 2][c0] = pk2(a.z * scale, c.z * scale);
    *(unsigned*)&tl[ts + 3][c0] = pk2(a.w * scale, c.w * scale);
  }
  __syncthreads();
  u16* dst = (role == 0 ? Qt : Kt) + (size_t)hh * T * CH;
#pragma unroll
  for (int q = 0; q < 2; ++q) {                        // 1KB/wave contiguous stores
    const int t = q * 32 + (tid >> 3);
    const int cc = (tid & 7) * 8;
    uint4 v = *(const uint4*)&tl[t][cc];
    *(uint4*)(dst + (size_t)(t0 + t) * CH + cc) = v;
  }
}

// ---------- flash attention v13: 8 waves = 4 t-groups (tq=2) x 2 s-groups ----------
// Same 16 KB K/V tiles as v12 (sg only selects WHICH half each wave reads - the
// xor swizzle is sg-invariant since +32 rows shifts it by 40 = 0 mod 8).
// Triple-buffered, counted vmcnt(2), 2 gl_lds/thread/STAGE. 24 waves/CU.
// Cross-sg partial (O, rowsum) combined once at epilogue via LDS reuse.
// grid (24 q-tiles, 32 heads), 512 threads; 48 KB LDS -> 3 blocks/CU.
__global__ __launch_bounds__(512, 6) void attn(
    const u16* __restrict__ Qt, const u16* __restrict__ Kt,
    const u16* __restrict__ Vg, float* __restrict__ out) {
  __shared__ __align__(16) u16 SMEM[24576];       // 48 KB
  u16* KBp = SMEM;                                // 3 x 4096 u16 (8 KB tiles)
  u16* VBp = SMEM + 12288;                        // 3 x 4096 u16

  const int qtile = blockIdx.x, hh = blockIdx.y;
  const int tid = threadIdx.x;
  const int wave = tid >> 6, lane = tid & 63;     // wave 0..7
  const int tg = wave & 3, sg = wave >> 2;        // t-group, s-group
  const int l15 = lane & 15, quad = lane >> 4;
  const int t0 = qtile * BM + tg * 32;            // 32 q-rows per t-group
  const int b = hh >> 3, h = hh & 7;

  const u16* Qh = Qt + (size_t)hh * T * CH;
  const u16* Kh = Kt + (size_t)hh * T * CH;
  const u16* Vh = Vg + (size_t)hh * CH * T;

  // Q B-frags resident: B[n=t=l15(+16tq)][k=kc*32+quad*8+j]
  short8 qf[2][2];
#pragma unroll
  for (int tq = 0; tq < 2; ++tq)
#pragma unroll
    for (int kc = 0; kc < 2; ++kc)
      qf[tq][kc] = *(const short8*)(Qh + (size_t)(t0 + tq * 16 + l15) * CH + kc * 32 + quad * 8);

  // all-ones bf16 B-frag for row-sum MFMA
  const short8 ones = {0x3F80, 0x3F80, 0x3F80, 0x3F80, 0x3F80, 0x3F80, 0x3F80, 0x3F80};

  floatx4 oacc[2][4] = {};
  floatx4 lacc[2] = {};

  // staging: 512 threads x 1 slot each per tensor; xor swizzle on source
  const int sr = tid >> 3;
  const int sc = (tid & 7) ^ ((sr + 2 * (sr >> 3)) & 7);
  const int swl = (l15 + 2 * (l15 >> 3)) & 7;
  const int wsl = (wave * 64) * 8;                // wave-uniform slot base (u16)

  // 2 gl_lds per thread per STAGE -> vmcnt unit is 2; 2 STAGEs in flight = 4.
#define STAGE(buf, s0)                                                              \
  do {                                                                              \
    gl_lds16(Kh + (size_t)((s0) + sr) * CH + sc * 8, &KBp[(buf) * 4096 + wsl]);     \
    gl_lds16(Vh + (size_t)sr * T + (s0) + sc * 8, &VBp[(buf) * 4096 + wsl]);        \
  } while (0)

  STAGE(0, 0);
  STAGE(1, BN);

  int cur = 0, nxt = 2;
  for (int it = 0; it < NIT; ++it) {
    if (it + 1 < NIT) {
      asm volatile("s_waitcnt vmcnt(2)" ::: "memory");   // tile it done; it+1 in flight
    } else {
      asm volatile("s_waitcnt vmcnt(0)" ::: "memory");
    }
    __builtin_amdgcn_s_barrier();                      // all waves: buf[cur] ready
    __builtin_amdgcn_sched_barrier(0);                 // pin ds_reads behind waitcnt
    if (it + 2 < NIT) STAGE(nxt, (it + 2) * BN);       // overwrites drained buf

    const u16* KL = KBp + cur * 4096;
    const u16* VL = VBp + cur * 4096;

    // S^T = K Q^T on this wave's s-half: rows sg*32 + nt*16 + l15, nt in {0,1}
    // sacc[tq][nt][r] = S[t=l15+16tq][s = sg*32 + nt*16 + quad*4 + r]
    floatx4 sacc[2][2];
    __builtin_amdgcn_s_setprio(1);
#pragma unroll
    for (int nt = 0; nt < 2; ++nt) {
      const int ph0 = quad ^ swl ^ (nt * 4);           // sg-invariant swizzle
      const int base = (sg * 32 + nt * 16 + l15) * CH;
      const short8 kf0 = *(const short8*)(KL + base + ph0 * 8);
      const short8 kf1 = *(const short8*)(KL + base + (ph0 ^ 4) * 8);
#pragma unroll
      for (int tq = 0; tq < 2; ++tq) {
        floatx4 z = {0.f, 0.f, 0.f, 0.f};
        z = __builtin_amdgcn_mfma_f32_16x16x32_bf16(kf0, qf[tq][0], z, 0, 0, 0);
        z = __builtin_amdgcn_mfma_f32_16x16x32_bf16(kf1, qf[tq][1], z, 0, 0, 0);
        sacc[tq][nt] = z;
      }
    }
    __builtin_amdgcn_s_setprio(0);

    // static softmax: packed P words stay in registers
    unsigned Apk[2][2], Bpk[2][2];
#pragma unroll
    for (int tq = 0; tq < 2; ++tq)
#pragma unroll
      for (int nt = 0; nt < 2; ++nt) {
        floatx4 sv = sacc[tq][nt];
        float p0 = __builtin_amdgcn_exp2f(sv[0]);
        float p1 = __builtin_amdgcn_exp2f(sv[1]);
        float p2 = __builtin_amdgcn_exp2f(sv[2]);
        float p3 = __builtin_amdgcn_exp2f(sv[3]);
        Apk[tq][nt] = pk2(p0, p1);
        Bpk[tq][nt] = pk2(p2, p3);
      }

    // O = P V^T on this wave's s-half (k = 32 values -> single A-frag per tq)
    __builtin_amdgcn_s_setprio(1);
    short8 pf[2];
#pragma unroll
    for (int tq = 0; tq < 2; ++tq) {
      unsigned a0 = Apk[tq][0], a1 = Apk[tq][1];
      unsigned b0 = Bpk[tq][0], b1 = Bpk[tq][1];
      pl32swap(a0, a1); pl16swap(a0, a1);   // a0 -> word d0, a1 -> word d2
      pl32swap(b0, b1); pl16swap(b0, b1);   // b0 -> word d1, b1 -> word d3
      union { uint4 u; short8 s; } pw;
      pw.u.x = a0; pw.u.y = b0; pw.u.z = a1; pw.u.w = b1;
      pf[tq] = pw.s;
      lacc[tq] = __builtin_amdgcn_mfma_f32_16x16x32_bf16(pf[tq], ones, lacc[tq], 0, 0, 0);
    }
#pragma unroll
    for (int mt = 0; mt < 4; ++mt) {
      const int ph = quad ^ swl ^ ((mt & 1) * 4) ^ (sg * 4);
      const short8 vf = *(const short8*)(VL + (mt * 16 + l15) * BN + ph * 8);
      oacc[0][mt] = __builtin_amdgcn_mfma_f32_16x16x32_bf16(pf[0], vf, oacc[0][mt], 0, 0, 0);
      oacc[1][mt] = __builtin_amdgcn_mfma_f32_16x16x32_bf16(pf[1], vf, oacc[1][mt], 0, 0, 0);
    }
    __builtin_amdgcn_s_setprio(0);

    cur = (cur == 2) ? 0 : cur + 1;
    nxt = (nxt == 2) ? 0 : nxt + 1;
  }

  // ---- cross-sg combine via LDS reuse (per tg: 2tq x (4 oacc + 1 lacc) x4B x64) ----
  __syncthreads();                        // all PV LDS reads done
  float* CMB = (float*)SMEM;              // 4 tg * 2560 floats = 40 KB <= 48
  float* reg = CMB + tg * 2560;
  if (sg == 1) {
#pragma unroll
    for (int tq = 0; tq < 2; ++tq) {
#pragma unroll
      for (int mt = 0; mt < 4; ++mt)
        *(floatx4*)(reg + ((tq * 5 + mt) * 64 + lane) * 4) = oacc[tq][mt];
      *(floatx4*)(reg + ((tq * 5 + 4) * 64 + lane) * 4) = lacc[tq];
    }
  }
  __syncthreads();
  if (sg == 0) {
#pragma unroll
    for (int tq = 0; tq < 2; ++tq) {
#pragma unroll
      for (int mt = 0; mt < 4; ++mt)
        oacc[tq][mt] += *(const floatx4*)(reg + ((tq * 5 + mt) * 64 + lane) * 4);
      lacc[tq] += *(const floatx4*)(reg + ((tq * 5 + 4) * 64 + lane) * 4);
    }

    float linv[2][4];
#pragma unroll
    for (int tq = 0; tq < 2; ++tq)
#pragma unroll
      for (int r = 0; r < 4; ++r) linv[tq][r] = 1.0f / lacc[tq][r];

    // O rows t = t0 + tq*16 + quad*4 + r ; cols c = mt*16 + l15 ; float4 over r
#pragma unroll
    for (int tq = 0; tq < 2; ++tq) {
      const int tgr = t0 + tq * 16 + quad * 4;
      const int band = tgr >> 10, tt = tgr & 1023;
      float* obase = out + (size_t)band * (4 * 512 * 1024)
                         + (size_t)b * (512 * 1024)
                         + (size_t)(h * CH) * 1024 + tt;
#pragma unroll
      for (int mt = 0; mt < 4; ++mt) {
        const int c = mt * 16 + l15;
        float4 v;
        v.x = oacc[tq][mt][0] * linv[tq][0];
        v.y = oacc[tq][mt][1] * linv[tq][1];
        v.z = oacc[tq][mt][2] * linv[tq][2];
        v.w = oacc[tq][mt][3] * linv[tq][3];
        *(float4*)(obase + (size_t)c * 1024) = v;
      }
    }
  }
}

extern "C" void kernel_launch(void* const* d_in, const int* in_sizes, int n_in,
                              void* d_out, int out_size, void* d_ws, size_t ws_size,
                              hipStream_t stream) {
  (void)in_sizes; (void)n_in; (void)out_size; (void)ws_size;
  const float* qkv = (const float*)d_in[0];
  u16* Qt = (u16*)d_ws;                                 // 3 x 12.6 MB bf16
  u16* Kt = Qt + (size_t)HEADS * T * CH;
  u16* Vo = Kt + (size_t)HEADS * T * CH;
  float* out = (float*)d_out;

  qktrans<<<dim3(T / 64, HEADS, 3), 256, 0, stream>>>(qkv, Qt, Kt, Vo);
  attn<<<dim3(T / BM, HEADS), 512, 0, stream>>>(Qt, Kt, Vo, out);
}

// Round 12
// 260.597 us; speedup vs baseline: 1.0591x; 1.0591x over previous
//
#include <hip/hip_runtime.h>
#include <hip/hip_bf16.h>
#include <stdint.h>

#define T      3072
#define CH     64
#define HEADS  32
#define BM     128
#define BN     64
#define NIT    (T / BN)

typedef unsigned short u16;
typedef short short8 __attribute__((ext_vector_type(8)));   // 8 bf16 as i16
typedef float floatx4 __attribute__((ext_vector_type(4)));

__device__ __forceinline__ unsigned pk2(float a, float b) {  // 2 fp32 -> packed bf16x2 (RNE)
  union { __hip_bfloat162 h; unsigned u; } cv;
  cv.h = __float22bfloat162_rn(float2{a, b});
  return cv.u;
}

__device__ __forceinline__ void gl_lds16(const void* g, void* l) {
  __builtin_amdgcn_global_load_lds(
      (const __attribute__((address_space(1))) uint32_t*)g,
      (__attribute__((address_space(3))) uint32_t*)l, 16, 0, 0);
}

// Cross-quad exchanges (VALU, gfx950): swap rows crosswise between two VGPRs.
__device__ __forceinline__ void pl32swap(unsigned& x, unsigned& y) {
#if __has_builtin(__builtin_amdgcn_permlane32_swap)
  auto r = __builtin_amdgcn_permlane32_swap(x, y, false, false);
  x = r[0]; y = r[1];
#else
  asm("v_permlane32_swap_b32 %0, %1" : "+v"(x), "+v"(y));
#endif
}
__device__ __forceinline__ void pl16swap(unsigned& x, unsigned& y) {
#if __has_builtin(__builtin_amdgcn_permlane16_swap)
  auto r = __builtin_amdgcn_permlane16_swap(x, y, false, false);
  x = r[0]; y = r[1];
#else
  asm("v_permlane16_swap_b32 %0, %1" : "+v"(x), "+v"(y));
#endif
}

// ---------- prepass: Q/K transpose (ch,t)->(t,ch) + V flat cast, all bf16 ----------
// grid (48 t-tiles, 32 heads, 3 roles), 256 threads   [round-3 verified version]
__global__ __launch_bounds__(256) void qktrans(
    const float* __restrict__ qkv, u16* __restrict__ Qt, u16* __restrict__ Kt,
    u16* __restrict__ Vo) {
  __shared__ __align__(16) u16 tl[64][72];            // [t][c], pad to 144B stride
  const int ttile = blockIdx.x, hh = blockIdx.y, role = blockIdx.z;
  const int b = hh >> 3, h = hh & 7;
  const int t0 = ttile * 64;
  const int tid = threadIdx.x;

  if (role == 2) {                                     // V: no transpose, flat cast
    const float* vsrc = qkv + (size_t)(b * 1536 + 1024 + h * CH) * T;
    u16* vdst = Vo + (size_t)(b * 512 + h * CH) * T;
#pragma unroll
    for (int p = 0; p < 2; ++p) {
      const int r = p * 32 + (tid >> 3);
      const int off = (tid & 7) * 8;
      const float4* s4 = (const float4*)(vsrc + (size_t)r * T + t0 + off);
      float4 a = s4[0], c = s4[1];
      uint4 o;
      o.x = pk2(a.x, a.y); o.y = pk2(a.z, a.w);
      o.z = pk2(c.x, c.y); o.w = pk2(c.z, c.w);
      *(uint4*)(vdst + (size_t)r * T + t0 + off) = o;
    }
    return;
  }

  const float* src = qkv + (size_t)(b * 1536 + role * 512 + h * CH) * T;
  const float scale = (role == 0) ? 0.18033688011112042f : 1.0f;  // (1/8)*log2e on Q

#pragma unroll
  for (int p = 0; p < 2; ++p) {                        // 32 c-rows per pass
    const int c0 = p * 32 + ((tid >> 4) << 1);         // even
    const int ts = (tid & 15) * 4;                     // 256B contiguous per c-row
    float4 a = *(const float4*)(src + (size_t)c0 * T + t0 + ts);
    float4 c = *(const float4*)(src + (size_t)(c0 + 1) * T + t0 + ts);
    *(unsigned*)&tl[ts + 0][c0] = pk2(a.x * scale, c.x * scale);
    *(unsigned*)&tl[ts + 1][c0] = pk2(a.y * scale, c.y * scale);
    *(unsigned*)&tl[ts + 2][c0] = pk2(a.z * scale, c.z * scale);
    *(unsigned*)&tl[ts + 3][c0] = pk2(a.w * scale, c.w * scale);
  }
  __syncthreads();
  u16* dst = (role == 0 ? Qt : Kt) + (size_t)hh * T * CH;
#pragma unroll
  for (int q = 0; q < 2; ++q) {                        // 1KB/wave contiguous stores
    const int t = q * 32 + (tid >> 3);
    const int cc = (tid & 7) * 8;
    uint4 v = *(const uint4*)&tl[t][cc];
    *(uint4*)(dst + (size_t)(t0 + t) * CH + cc) = v;
  }
}

// ---------- flash attention v14: K fragments DIRECT from global (coalesced ----------
// 128B-stride rows, L1/L2-resident, register-rotated prefetch); V via 16 KB ----------
// LDS double-buffer.  K-path is barrier-free; LDS traffic halves vs v12.    ----------
// grid (24 q-tiles, 32 heads), 256 threads = 4 waves, tq=2 (32 rows/wave).
__global__ __launch_bounds__(256, 3) void attn(
    const u16* __restrict__ Qt, const u16* __restrict__ Kt,
    const u16* __restrict__ Vg, float* __restrict__ out) {
  __shared__ __align__(16) u16 VB[2][CH * BN];    // [c][s] 8 KB each, xor-swizzled

  const int qtile = blockIdx.x, hh = blockIdx.y;
  const int tid = threadIdx.x;
  const int wave = tid >> 6, lane = tid & 63;     // wave 0..3
  const int l15 = lane & 15, quad = lane >> 4;
  const int t0 = qtile * BM + wave * 32;          // 32 q-rows per wave
  const int b = hh >> 3, h = hh & 7;

  const u16* Qh = Qt + (size_t)hh * T * CH;
  const u16* Kh = Kt + (size_t)hh * T * CH;
  const u16* Vh = Vg + (size_t)hh * CH * T;

  // Q B-frags resident: B[n=t=l15(+16tq)][k=kc*32+quad*8+j]
  short8 qf[2][2];
#pragma unroll
  for (int tq = 0; tq < 2; ++tq)
#pragma unroll
    for (int kc = 0; kc < 2; ++kc)
      qf[tq][kc] = *(const short8*)(Qh + (size_t)(t0 + tq * 16 + l15) * CH + kc * 32 + quad * 8);

  // all-ones bf16 B-frag for row-sum MFMA
  const short8 ones = {0x3F80, 0x3F80, 0x3F80, 0x3F80, 0x3F80, 0x3F80, 0x3F80, 0x3F80};

  floatx4 oacc[2][4] = {};
  floatx4 lacc[2] = {};

  // V staging: 512 16B-slots, 2 per thread; swizzle phys_cb = cb ^ ((row+2*(row>>3))&7)
  int sr[2], sc[2];
#pragma unroll
  for (int j = 0; j < 2; ++j) {
    const int p = j * 256 + wave * 64 + lane;
    sr[j] = p >> 3;
    sc[j] = (p & 7) ^ ((sr[j] + 2 * (sr[j] >> 3)) & 7);
  }
  const int swl = (l15 + 2 * (l15 >> 3)) & 7;

#define STAGE_V(buf, s0)                                                            \
  do {                                                                              \
    _Pragma("unroll")                                                               \
    for (int j = 0; j < 2; ++j)                                                     \
      gl_lds16(Vh + (size_t)sr[j] * T + (s0) + sc[j] * 8,                           \
               &VB[buf][(j * 256 + wave * 64) * 8]);                                \
  } while (0)

  // K A-frags direct from global: A[m = nt*16+l15][k = kc*32+quad*8+j]
  // addr = (it*BN + nt*16 + l15)*CH + kc*32 + quad*8 -> wave reads 2KB contiguous
  const u16* Kp = Kh + (size_t)l15 * CH + quad * 8;
  short8 kf[4][2];
#define LOADK(it_)                                                                  \
  do {                                                                              \
    const u16* kb_ = Kp + (size_t)(it_) * BN * CH;                                  \
    _Pragma("unroll")                                                               \
    for (int nt = 0; nt < 4; ++nt) {                                                \
      kf[nt][0] = *(const short8*)(kb_ + (size_t)nt * 16 * CH);                     \
      kf[nt][1] = *(const short8*)(kb_ + (size_t)nt * 16 * CH + 32);                \
    }                                                                               \
  } while (0)

  STAGE_V(0, 0);
  LOADK(0);

  for (int it = 0; it < NIT; ++it) {
    const int cur = it & 1;
    __syncthreads();                                   // VB[cur] ready; kf(it) landed
    if (it + 1 < NIT) STAGE_V(cur ^ 1, (it + 1) * BN); // async prefetch

    // S^T = K Q^T : A=K frag (regs, from global), B=Q frag (regs).
    // sacc[tq][nt][r] = S[t = l15+16tq][s = nt*16 + quad*4 + r]
    floatx4 sacc[2][4];
    __builtin_amdgcn_s_setprio(1);
#pragma unroll
    for (int nt = 0; nt < 4; ++nt) {
#pragma unroll
      for (int tq = 0; tq < 2; ++tq) {
        floatx4 z = {0.f, 0.f, 0.f, 0.f};
        z = __builtin_amdgcn_mfma_f32_16x16x32_bf16(kf[nt][0], qf[tq][0], z, 0, 0, 0);
        z = __builtin_amdgcn_mfma_f32_16x16x32_bf16(kf[nt][1], qf[tq][1], z, 0, 0, 0);
        sacc[tq][nt] = z;
      }
    }
    __builtin_amdgcn_s_setprio(0);

    // rotate K: load tile it+1 into kf (after last use); lands during sm+PV+barrier
    if (it + 1 < NIT) LOADK(it + 1);

    // static softmax: packed P words stay in registers
    unsigned Apk[2][4], Bpk[2][4];
#pragma unroll
    for (int tq = 0; tq < 2; ++tq)
#pragma unroll
      for (int nt = 0; nt < 4; ++nt) {
        floatx4 sv = sacc[tq][nt];
        float p0 = __builtin_amdgcn_exp2f(sv[0]);
        float p1 = __builtin_amdgcn_exp2f(sv[1]);
        float p2 = __builtin_amdgcn_exp2f(sv[2]);
        float p3 = __builtin_amdgcn_exp2f(sv[3]);
        Apk[tq][nt] = pk2(p0, p1);
        Bpk[tq][nt] = pk2(p2, p3);
      }

    // O = P V^T : A=P via permlane swaps; V frags from swizzled LDS (shared by tq).
    const u16* VL = VB[cur];
    __builtin_amdgcn_s_setprio(1);
#pragma unroll
    for (int ks = 0; ks < 2; ++ks) {
      short8 pf[2];
#pragma unroll
      for (int tq = 0; tq < 2; ++tq) {
        unsigned a0 = Apk[tq][2 * ks], a1 = Apk[tq][2 * ks + 1];
        unsigned b0 = Bpk[tq][2 * ks], b1 = Bpk[tq][2 * ks + 1];
        pl32swap(a0, a1); pl16swap(a0, a1);   // a0 -> word d0, a1 -> word d2
        pl32swap(b0, b1); pl16swap(b0, b1);   // b0 -> word d1, b1 -> word d3
        union { uint4 u; short8 s; } pw;
        pw.u.x = a0; pw.u.y = b0; pw.u.z = a1; pw.u.w = b1;
        pf[tq] = pw.s;
        lacc[tq] = __builtin_amdgcn_mfma_f32_16x16x32_bf16(pf[tq], ones, lacc[tq], 0, 0, 0);
      }
#pragma unroll
      for (int mt = 0; mt < 4; ++mt) {
        const int ph = quad ^ swl ^ ((mt & 1) * 4) ^ (ks * 4);
        const short8 vf = *(const short8*)(VL + (mt * 16 + l15) * BN + ph * 8);
        oacc[0][mt] = __builtin_amdgcn_mfma_f32_16x16x32_bf16(pf[0], vf, oacc[0][mt], 0, 0, 0);
        oacc[1][mt] = __builtin_amdgcn_mfma_f32_16x16x32_bf16(pf[1], vf, oacc[1][mt], 0, 0, 0);
      }
    }
    __builtin_amdgcn_s_setprio(0);
  }

  // epilogue: lacc[tq][r] holds rowsum(t = t0 + tq*16 + quad*4 + r) per l15 col
  float linv[2][4];
#pragma unroll
  for (int tq = 0; tq < 2; ++tq)
#pragma unroll
    for (int r = 0; r < 4; ++r) linv[tq][r] = 1.0f / lacc[tq][r];

  // O rows t = t0 + tq*16 + quad*4 + r ; cols c = mt*16 + l15 ; float4 over r
#pragma unroll
  for (int tq = 0; tq < 2; ++tq) {
    const int tgr = t0 + tq * 16 + quad * 4;
    const int band = tgr >> 10, tt = tgr & 1023;
    float* obase = out + (size_t)band * (4 * 512 * 1024)
                       + (size_t)b * (512 * 1024)
                       + (size_t)(h * CH) * 1024 + tt;
#pragma unroll
    for (int mt = 0; mt < 4; ++mt) {
      const int c = mt * 16 + l15;
      float4 v;
      v.x = oacc[tq][mt][0] * linv[tq][0];
      v.y = oacc[tq][mt][1] * linv[tq][1];
      v.z = oacc[tq][mt][2] * linv[tq][2];
      v.w = oacc[tq][mt][3] * linv[tq][3];
      *(float4*)(obase + (size_t)c * 1024) = v;
    }
  }
}

extern "C" void kernel_launch(void* const* d_in, const int* in_sizes, int n_in,
                              void* d_out, int out_size, void* d_ws, size_t ws_size,
                              hipStream_t stream) {
  (void)in_sizes; (void)n_in; (void)out_size; (void)ws_size;
  const float* qkv = (const float*)d_in[0];
  u16* Qt = (u16*)d_ws;                                 // 3 x 12.6 MB bf16
  u16* Kt = Qt + (size_t)HEADS * T * CH;
  u16* Vo = Kt + (size_t)HEADS * T * CH;
  float* out = (float*)d_out;

  qktrans<<<dim3(T / 64, HEADS, 3), 256, 0, stream>>>(qkv, Qt, Kt, Vo);
  attn<<<dim3(T / BM, HEADS), 256, 0, stream>>>(Qt, Kt, Vo, out);
}

// Round 13
// 211.987 us; speedup vs baseline: 1.3020x; 1.2293x over previous
//
#include <hip/hip_runtime.h>
#include <hip/hip_bf16.h>
#include <stdint.h>

#define T      3072
#define CH     64
#define HEADS  32
#define BM     128
#define BN     64
#define NIT    (T / BN)

typedef unsigned short u16;
typedef short short8 __attribute__((ext_vector_type(8)));   // 8 bf16 as i16
typedef float floatx4 __attribute__((ext_vector_type(4)));

__device__ __forceinline__ unsigned pk2(float a, float b) {  // 2 fp32 -> packed bf16x2 (RNE)
  union { __hip_bfloat162 h; unsigned u; } cv;
  cv.h = __float22bfloat162_rn(float2{a, b});
  return cv.u;
}

__device__ __forceinline__ void gl_lds16(const void* g, void* l) {
  __builtin_amdgcn_global_load_lds(
      (const __attribute__((address_space(1))) uint32_t*)g,
      (__attribute__((address_space(3))) uint32_t*)l, 16, 0, 0);
}

// Cross-quad exchanges (VALU, gfx950): swap rows crosswise between two VGPRs.
__device__ __forceinline__ void pl32swap(unsigned& x, unsigned& y) {
#if __has_builtin(__builtin_amdgcn_permlane32_swap)
  auto r = __builtin_amdgcn_permlane32_swap(x, y, false, false);
  x = r[0]; y = r[1];
#else
  asm("v_permlane32_swap_b32 %0, %1" : "+v"(x), "+v"(y));
#endif
}
__device__ __forceinline__ void pl16swap(unsigned& x, unsigned& y) {
#if __has_builtin(__builtin_amdgcn_permlane16_swap)
  auto r = __builtin_amdgcn_permlane16_swap(x, y, false, false);
  x = r[0]; y = r[1];
#else
  asm("v_permlane16_swap_b32 %0, %1" : "+v"(x), "+v"(y));
#endif
}

// ---------- prepass: Q/K transpose (ch,t)->(t,ch) + V flat cast, all bf16 ----------
// grid (48 t-tiles, 32 heads, 3 roles), 256 threads   [round-3 verified version]
__global__ __launch_bounds__(256) void qktrans(
    const float* __restrict__ qkv, u16* __restrict__ Qt, u16* __restrict__ Kt,
    u16* __restrict__ Vo) {
  __shared__ __align__(16) u16 tl[64][72];            // [t][c], pad to 144B stride
  const int ttile = blockIdx.x, hh = blockIdx.y, role = blockIdx.z;
  const int b = hh >> 3, h = hh & 7;
  const int t0 = ttile * 64;
  const int tid = threadIdx.x;

  if (role == 2) {                                     // V: no transpose, flat cast
    const float* vsrc = qkv + (size_t)(b * 1536 + 1024 + h * CH) * T;
    u16* vdst = Vo + (size_t)(b * 512 + h * CH) * T;
#pragma unroll
    for (int p = 0; p < 2; ++p) {
      const int r = p * 32 + (tid >> 3);
      const int off = (tid & 7) * 8;
      const float4* s4 = (const float4*)(vsrc + (size_t)r * T + t0 + off);
      float4 a = s4[0], c = s4[1];
      uint4 o;
      o.x = pk2(a.x, a.y); o.y = pk2(a.z, a.w);
      o.z = pk2(c.x, c.y); o.w = pk2(c.z, c.w);
      *(uint4*)(vdst + (size_t)r * T + t0 + off) = o;
    }
    return;
  }

  const float* src = qkv + (size_t)(b * 1536 + role * 512 + h * CH) * T;
  const float scale = (role == 0) ? 0.18033688011112042f : 1.0f;  // (1/8)*log2e on Q

#pragma unroll
  for (int p = 0; p < 2; ++p) {                        // 32 c-rows per pass
    const int c0 = p * 32 + ((tid >> 4) << 1);         // even
    const int ts = (tid & 15) * 4;                     // 256B contiguous per c-row
    float4 a = *(const float4*)(src + (size_t)c0 * T + t0 + ts);
    float4 c = *(const float4*)(src + (size_t)(c0 + 1) * T + t0 + ts);
    *(unsigned*)&tl[ts + 0][c0] = pk2(a.x * scale, c.x * scale);
    *(unsigned*)&tl[ts + 1][c0] = pk2(a.y * scale, c.y * scale);
    *(unsigned*)&tl[ts + 2][c0] = pk2(a.z * scale, c.z * scale);
    *(unsigned*)&tl[ts + 3][c0] = pk2(a.w * scale, c.w * scale);
  }
  __syncthreads();
  u16* dst = (role == 0 ? Qt : Kt) + (size_t)hh * T * CH;
#pragma unroll
  for (int q = 0; q < 2; ++q) {                        // 1KB/wave contiguous stores
    const int t = q * 32 + (tid >> 3);
    const int cc = (tid & 7) * 8;
    uint4 v = *(const uint4*)&tl[t][cc];
    *(uint4*)(dst + (size_t)(t0 + t) * CH + cc) = v;
  }
}

// ---------- flash attention v12 (RESTORED - best measured: attn 111 us) ----------
// tq=2 (32 rows/wave), 4-wave blocks, triple-buffered K/V, counted vmcnt(4),
// P in regs via permlane, row-sums on MFMA pipe, setprio around MFMA clusters.
// launch_bounds(256,3) -> 170 VGPR cap, no spill.  48 KB LDS -> 3 blocks/CU.
// grid (24 q-tiles, 32 heads), 256 threads = 4 waves.
__global__ __launch_bounds__(256, 3) void attn(
    const u16* __restrict__ Qt, const u16* __restrict__ Kt,
    const u16* __restrict__ Vg, float* __restrict__ out) {
  __shared__ __align__(16) u16 KB[3][BN * CH];    // [s][c] 8 KB each, xor-swizzled
  __shared__ __align__(16) u16 VB[3][CH * BN];    // [c][s] 8 KB each, xor-swizzled

  const int qtile = blockIdx.x, hh = blockIdx.y;
  const int tid = threadIdx.x;
  const int wave = tid >> 6, lane = tid & 63;     // wave 0..3
  const int l15 = lane & 15, quad = lane >> 4;
  const int t0 = qtile * BM + wave * 32;          // 32 q-rows per wave
  const int b = hh >> 3, h = hh & 7;

  const u16* Qh = Qt + (size_t)hh * T * CH;
  const u16* Kh = Kt + (size_t)hh * T * CH;
  const u16* Vh = Vg + (size_t)hh * CH * T;

  // Q B-frags resident: B[n=t=l15(+16tq)][k=kc*32+quad*8+j]
  short8 qf[2][2];
#pragma unroll
  for (int tq = 0; tq < 2; ++tq)
#pragma unroll
    for (int kc = 0; kc < 2; ++kc)
      qf[tq][kc] = *(const short8*)(Qh + (size_t)(t0 + tq * 16 + l15) * CH + kc * 32 + quad * 8);

  // all-ones bf16 B-frag for row-sum MFMA
  const short8 ones = {0x3F80, 0x3F80, 0x3F80, 0x3F80, 0x3F80, 0x3F80, 0x3F80, 0x3F80};

  floatx4 oacc[2][4] = {};
  floatx4 lacc[2] = {};

  // staging: 512 16B-slots per tensor, 2 K + 2 V per thread (issue j covers
  // slots j*256 + wave*64 + lane); swizzle phys_cb = cb ^ ((row + 2*(row>>3))&7)
  int sr[2], sc[2];
#pragma unroll
  for (int j = 0; j < 2; ++j) {
    const int p = j * 256 + wave * 64 + lane;
    sr[j] = p >> 3;
    sc[j] = (p & 7) ^ ((sr[j] + 2 * (sr[j] >> 3)) & 7);
  }
  const int swl = (l15 + 2 * (l15 >> 3)) & 7;

  // 4 gl_lds per thread per STAGE -> vmcnt unit is 4; 2 STAGEs in flight = 8.
#define STAGE(buf, s0)                                                              \
  do {                                                                              \
    _Pragma("unroll")                                                               \
    for (int j = 0; j < 2; ++j)                                                     \
      gl_lds16(Kh + (size_t)((s0) + sr[j]) * CH + sc[j] * 8,                        \
               &KB[buf][(j * 256 + wave * 64) * 8]);                                \
    _Pragma("unroll")                                                               \
    for (int j = 0; j < 2; ++j)                                                     \
      gl_lds16(Vh + (size_t)sr[j] * T + (s0) + sc[j] * 8,                           \
               &VB[buf][(j * 256 + wave * 64) * 8]);                                \
  } while (0)

  STAGE(0, 0);
  STAGE(1, BN);

  int cur = 0, nxt = 2;                                // compute buf, stage buf
  for (int it = 0; it < NIT; ++it) {
    // tile it's 4 loads are the oldest outstanding; leave tile it+1's in flight.
    if (it + 1 < NIT) {
      asm volatile("s_waitcnt vmcnt(4)" ::: "memory");
    } else {
      asm volatile("s_waitcnt vmcnt(0)" ::: "memory");
    }
    __builtin_amdgcn_s_barrier();                      // all waves: buf[cur] ready
    __builtin_amdgcn_sched_barrier(0);                 // pin ds_reads behind waitcnt
    if (it + 2 < NIT) STAGE(nxt, (it + 2) * BN);       // overwrites buf[(it-1)%3]: drained

    const u16* KL = KB[cur];
    const u16* VL = VB[cur];

    // S^T = K Q^T : A=K frag (LDS, shared by both tq), B=Q frag (regs).
    // sacc[tq][nt][r] = S[t = l15+16tq][s = nt*16 + quad*4 + r]
    floatx4 sacc[2][4];
    __builtin_amdgcn_s_setprio(1);
#pragma unroll
    for (int nt = 0; nt < 4; ++nt) {
      const int ph0 = quad ^ swl ^ ((nt & 1) * 4);
      const int base = (nt * 16 + l15) * CH;
      const short8 kf0 = *(const short8*)(KL + base + ph0 * 8);
      const short8 kf1 = *(const short8*)(KL + base + (ph0 ^ 4) * 8);
#pragma unroll
      for (int tq = 0; tq < 2; ++tq) {
        floatx4 z = {0.f, 0.f, 0.f, 0.f};
        z = __builtin_amdgcn_mfma_f32_16x16x32_bf16(kf0, qf[tq][0], z, 0, 0, 0);
        z = __builtin_amdgcn_mfma_f32_16x16x32_bf16(kf1, qf[tq][1], z, 0, 0, 0);
        sacc[tq][nt] = z;
      }
    }
    __builtin_amdgcn_s_setprio(0);

    // static softmax: packed P words stay in registers
    unsigned Apk[2][4], Bpk[2][4];
#pragma unroll
    for (int tq = 0; tq < 2; ++tq)
#pragma unroll
      for (int nt = 0; nt < 4; ++nt) {
        floatx4 sv = sacc[tq][nt];
        float p0 = __builtin_amdgcn_exp2f(sv[0]);
        float p1 = __builtin_amdgcn_exp2f(sv[1]);
        float p2 = __builtin_amdgcn_exp2f(sv[2]);
        float p3 = __builtin_amdgcn_exp2f(sv[3]);
        Apk[tq][nt] = pk2(p0, p1);
        Bpk[tq][nt] = pk2(p2, p3);
      }

    // O = P V^T : A=P via permlane swaps; each V frag read serves both tq.
    __builtin_amdgcn_s_setprio(1);
#pragma unroll
    for (int ks = 0; ks < 2; ++ks) {
      short8 pf[2];
#pragma unroll
      for (int tq = 0; tq < 2; ++tq) {
        unsigned a0 = Apk[tq][2 * ks], a1 = Apk[tq][2 * ks + 1];
        unsigned b0 = Bpk[tq][2 * ks], b1 = Bpk[tq][2 * ks + 1];
        pl32swap(a0, a1); pl16swap(a0, a1);   // a0 -> word d0, a1 -> word d2
        pl32swap(b0, b1); pl16swap(b0, b1);   // b0 -> word d1, b1 -> word d3
        union { uint4 u; short8 s; } pw;
        pw.u.x = a0; pw.u.y = b0; pw.u.z = a1; pw.u.w = b1;
        pf[tq] = pw.s;
        lacc[tq] = __builtin_amdgcn_mfma_f32_16x16x32_bf16(pf[tq], ones, lacc[tq], 0, 0, 0);
      }
#pragma unroll
      for (int mt = 0; mt < 4; ++mt) {
        const int ph = quad ^ swl ^ ((mt & 1) * 4) ^ (ks * 4);
        const short8 vf = *(const short8*)(VL + (mt * 16 + l15) * BN + ph * 8);
        oacc[0][mt] = __builtin_amdgcn_mfma_f32_16x16x32_bf16(pf[0], vf, oacc[0][mt], 0, 0, 0);
        oacc[1][mt] = __builtin_amdgcn_mfma_f32_16x16x32_bf16(pf[1], vf, oacc[1][mt], 0, 0, 0);
      }
    }
    __builtin_amdgcn_s_setprio(0);

    cur = (cur == 2) ? 0 : cur + 1;
    nxt = (nxt == 2) ? 0 : nxt + 1;
  }

  // epilogue: lacc[tq][r] holds rowsum(t = t0 + tq*16 + quad*4 + r) per l15 col
  float linv[2][4];
#pragma unroll
  for (int tq = 0; tq < 2; ++tq)
#pragma unroll
    for (int r = 0; r < 4; ++r) linv[tq][r] = 1.0f / lacc[tq][r];

  // O rows t = t0 + tq*16 + quad*4 + r ; cols c = mt*16 + l15 ; float4 over r
#pragma unroll
  for (int tq = 0; tq < 2; ++tq) {
    const int tgr = t0 + tq * 16 + quad * 4;
    const int band = tgr >> 10, tt = tgr & 1023;
    float* obase = out + (size_t)band * (4 * 512 * 1024)
                       + (size_t)b * (512 * 1024)
                       + (size_t)(h * CH) * 1024 + tt;
#pragma unroll
    for (int mt = 0; mt < 4; ++mt) {
      const int c = mt * 16 + l15;
      float4 v;
      v.x = oacc[tq][mt][0] * linv[tq][0];
      v.y = oacc[tq][mt][1] * linv[tq][1];
      v.z = oacc[tq][mt][2] * linv[tq][2];
      v.w = oacc[tq][mt][3] * linv[tq][3];
      *(float4*)(obase + (size_t)c * 1024) = v;
    }
  }
}

extern "C" void kernel_launch(void* const* d_in, const int* in_sizes, int n_in,
                              void* d_out, int out_size, void* d_ws, size_t ws_size,
                              hipStream_t stream) {
  (void)in_sizes; (void)n_in; (void)out_size; (void)ws_size;
  const float* qkv = (const float*)d_in[0];
  u16* Qt = (u16*)d_ws;                                 // 3 x 12.6 MB bf16
  u16* Kt = Qt + (size_t)HEADS * T * CH;
  u16* Vo = Kt + (size_t)HEADS * T * CH;
  float* out = (float*)d_out;

  qktrans<<<dim3(T / 64, HEADS, 3), 256, 0, stream>>>(qkv, Qt, Kt, Vo);
  attn<<<dim3(T / BM, HEADS), 256, 0, stream>>>(Qt, Kt, Vo, out);
}